// Round 23
// baseline (90.863 us; speedup 1.0000x reference)
//
#include <hip/hip_runtime.h>
#include <math.h>

constexpr int B  = 128;
constexpr int R  = 4096;
constexpr int IC = 8;
constexpr int C  = 10;
constexpr int O  = 16;
constexpr int CO = C * O;        // 160

constexpr int RCH    = 16;       // r's per pass0 chunk (proven geometry)
constexpr int NCHUNK = R / RCH;  // 256
constexpr int RH     = 8;        // r's per routing-pass block (half chunk)
constexpr int NSLOT  = R / RH;   // 512 routing-pass slots

using f16x8 = __attribute__((ext_vector_type(8))) _Float16;
using f16x4 = __attribute__((ext_vector_type(4))) _Float16;
using f32x4 = __attribute__((ext_vector_type(4))) float;

// DPP add (VALU). row_ror:N = 0x120|N rotates within each 16-lane row.
template<int CTRL>
__device__ __forceinline__ float dpp_add(float v) {
    return v + __int_as_float(__builtin_amdgcn_update_dpp(
        0, __float_as_int(v), CTRL, 0xF, 0xF, true));
}
__device__ __forceinline__ float rowsum16(float v) {
    v = dpp_add<0x121>(v); v = dpp_add<0x122>(v);
    v = dpp_add<0x124>(v); v = dpp_add<0x128>(v);
    return v;
}

// Butterfly sum over lane^16 / lane^32 (proven DS path).
__device__ __forceinline__ float sum_kb(float p) {
    p += __int_as_float(__builtin_amdgcn_ds_swizzle(__float_as_int(p), 0x401F));
    p += __shfl_xor(p, 32, 64);
    return p;
}

// ---- pass 0 with fused conversion (R22-proven). Per (chunk, bhalf) block:
// convert W fp32 slice -> wlds (+W16 once); x -> xlds (+xT16); K-packed GEMM. ----
__global__ __launch_bounds__(256, 2)
void pass0_fused(const float* __restrict__ x, const float* __restrict__ W,
                 _Float16* __restrict__ W16, _Float16* __restrict__ xT16,
                 _Float16* __restrict__ s_part)
{
    __shared__ _Float16 wlds[RCH * C * O * IC];   // 40 KB: W[r][c][o][i]
    __shared__ _Float16 xlds[RCH * 64 * IC];      // 16 KB: x[r][b-local][i]

    const int tid = threadIdx.x;
    const int wv  = tid >> 6;
    const int l   = tid & 63;
    const int ln  = l & 15;
    const int kb  = l >> 4;

    const int g     = blockIdx.x;
    const int xcd   = g & 7;
    const int t     = g >> 3;          // 0..63
    const int bhalf = t & 1;
    const int cid   = t >> 1;          // 0..31
    const int chunk = xcd * 32 + cid;  // 0..255
    const int b     = bhalf * 64 + wv * 16 + ln;
    const int b0    = bhalf * 64;
    const int r0    = chunk * RCH;

    // ---- W slice: 20480 fp32 read coalesced, convert, stage + global write ----
    {
        const float* wsrc = W + (size_t)r0 * (C * O * IC);
        _Float16*    wdst = W16 + (size_t)r0 * (C * O * IC);
        #pragma unroll
        for (int k = 0; k < 20; ++k) {
            const int idx = (k * 256 + tid) * 4;
            float4 v = *reinterpret_cast<const float4*>(wsrc + idx);
            f16x4 h = {(_Float16)v.x, (_Float16)v.y, (_Float16)v.z, (_Float16)v.w};
            *reinterpret_cast<f16x4*>(&wlds[idx]) = h;
            if (bhalf == 0)
                *reinterpret_cast<f16x4*>(wdst + idx) = h;   // once per chunk
        }
    }
    // ---- x slice: 64 b-rows x 512B contiguous, convert+transpose into xlds ----
    {
        #pragma unroll
        for (int k = 0; k < 8; ++k) {
            const int w2 = k * 256 + tid;       // (bi, f4): 64 x 32 work items
            const int bi = w2 >> 5, f4 = w2 & 31;
            const int r = f4 >> 1, i4 = f4 & 1;
            float4 v = *reinterpret_cast<const float4*>(
                x + ((size_t)(b0 + bi) * R + r0 + r) * IC + i4 * 4);
            f16x4 h = {(_Float16)v.x, (_Float16)v.y, (_Float16)v.z, (_Float16)v.w};
            *reinterpret_cast<f16x4*>(&xlds[(r * 64 + bi) * IC + i4 * 4]) = h;
        }
    }
    __syncthreads();
    // ---- write xT16 (for passes 1,2) coalesced from xlds ----
    {
        #pragma unroll
        for (int k = 0; k < 4; ++k) {
            const int w2 = k * 256 + tid;       // 0..1023: (r, b-local)
            const int r = w2 >> 6, v = w2 & 63;
            *reinterpret_cast<f16x8*>(
                xT16 + ((size_t)(r0 + r) * B + b0 + v) * IC) =
                *reinterpret_cast<const f16x8*>(&xlds[(r * 64 + v) * IC]);
        }
    }

    // ---- K-packed GEMM from LDS (proven) ----
    f32x4 sacc[C];
    #pragma unroll
    for (int c = 0; c < C; ++c) sacc[c] = (f32x4){0.f, 0.f, 0.f, 0.f};

    const int bloc = wv * 16 + ln;

    #pragma unroll 2
    for (int rp = 0; rp < RCH / 4; ++rp) {
        const int r = rp * 4 + kb;
        const f16x8 bf = *reinterpret_cast<const f16x8*>(&xlds[(r * 64 + bloc) * IC]);
        #pragma unroll
        for (int c = 0; c < C; ++c) {
            f16x8 af = *reinterpret_cast<const f16x8*>(
                &wlds[((r * C + c) * O + ln) * IC]);
            sacc[c] = __builtin_amdgcn_mfma_f32_16x16x32_f16(af, bf, sacc[c], 0, 0, 0);
        }
    }

    _Float16* sp = s_part + ((size_t)chunk * B + b) * CO + kb * 4;
    #pragma unroll
    for (int c = 0; c < C; ++c) {
        f16x4 h = {(_Float16)(sacc[c][0] * 0.1f), (_Float16)(sacc[c][1] * 0.1f),
                   (_Float16)(sacc[c][2] * 0.1f), (_Float16)(sacc[c][3] * 0.1f)};
        *reinterpret_cast<f16x4*>(sp + c * O) = h;
    }
}

// ---- routing pass (iters 1,2): RH=8 half-chunk blocks for occupancy ----
// LDS 28 KB -> 3 blocks/CU at (256,3) = 12 waves/CU (was 2 blocks/8 waves).
// Same LDS-staged structure as R19/R22; grid 1024; slot = xcd*64 + cid.
template<int IT>
__global__ __launch_bounds__(256, 3)
void pass_mfma(const _Float16* __restrict__ W16, const _Float16* __restrict__ xT16,
               const float* __restrict__ vsum, _Float16* __restrict__ s_part)
{
    __shared__ _Float16 wlds[RH * C * O * IC];   // 20 KB: W[r][c][o][i]
    __shared__ _Float16 xlds[RH * 64 * IC];      // 8 KB:  x[r][b-local][i]

    const int tid = threadIdx.x;
    const int wv  = tid >> 6;
    const int l   = tid & 63;
    const int ln  = l & 15;
    const int kb  = l >> 4;

    const int g     = blockIdx.x;
    const int xcd   = g & 7;
    const int t     = g >> 3;          // 0..127
    const int bhalf = t & 1;
    const int cid   = t >> 1;          // 0..63
    const int slot  = xcd * 64 + cid;  // 0..511
    const int b     = bhalf * 64 + wv * 16 + ln;
    const int r0    = slot * RH;

    // ---- stage W slice: 10240 halves, 5 sweeps x 256 thr x 16B, coalesced ----
    {
        const _Float16* wsrc = W16 + (size_t)r0 * (C * O * IC);
        #pragma unroll
        for (int k = 0; k < 5; ++k) {
            const int idx = (k * 256 + tid) * 8;
            *reinterpret_cast<f16x8*>(&wlds[idx]) =
                *reinterpret_cast<const f16x8*>(wsrc + idx);
        }
    }
    // ---- stage x slice: 8 r-rows x 64 b x 8i, 2 sweeps, coalesced ----
    {
        #pragma unroll
        for (int k = 0; k < 2; ++k) {
            const int w2 = k * 256 + tid;       // 0..511: (r, b-local)
            const int r = w2 >> 6, lx = w2 & 63;
            *reinterpret_cast<f16x8*>(&xlds[(r * 64 + lx) * IC]) =
                *reinterpret_cast<const f16x8*>(
                    xT16 + ((size_t)(r0 + r) * B + bhalf * 64 + lx) * IC);
        }
    }

    float vreg[C][4];                  // v[b][c][o = kb*4 + j]
    #pragma unroll
    for (int c = 0; c < C; ++c)
        *reinterpret_cast<float4*>(vreg[c]) =
            *reinterpret_cast<const float4*>(vsum + (size_t)b * CO + c * O + kb * 4);

    f32x4 sacc[C];
    #pragma unroll
    for (int c = 0; c < C; ++c) sacc[c] = (f32x4){0.f, 0.f, 0.f, 0.f};

    __syncthreads();                   // staged operands visible

    const int bloc = wv * 16 + ln;     // local b index (0..63)

    #pragma unroll 2
    for (int rr = 0; rr < RH; ++rr) {
        f16x8 bf;
        #pragma unroll
        for (int j = 0; j < 8; ++j) bf[j] = (_Float16)0.f;
        if (kb == 0)
            bf = *reinterpret_cast<const f16x8*>(&xlds[(rr * 64 + bloc) * IC]);

        f32x4 uh[C];
        #pragma unroll
        for (int c = 0; c < C; ++c) {
            f16x8 af = *reinterpret_cast<const f16x8*>(
                &wlds[((rr * C + c) * O + ln) * IC]);
            uh[c] = __builtin_amdgcn_mfma_f32_16x16x32_f16(
                        af, bf, (f32x4){0.f, 0.f, 0.f, 0.f}, 0, 0, 0);
        }

        // logits a[b,c] = sum_o uh*v: 4 in-lane FMA + DS butterfly
        float a[C];
        #pragma unroll
        for (int c = 0; c < C; ++c) {
            float p = uh[c][0] * vreg[c][0];
            p = fmaf(uh[c][1], vreg[c][1], p);
            p = fmaf(uh[c][2], vreg[c][2], p);
            p = fmaf(uh[c][3], vreg[c][3], p);
            a[c] = sum_kb(p);
        }
        // softmax over c (logits small: no max-subtract), rcp divide
        float sum = 0.f;
        #pragma unroll
        for (int c = 0; c < C; ++c) { a[c] = __expf(a[c]); sum += a[c]; }
        const float inv = __builtin_amdgcn_rcpf(sum);
        #pragma unroll
        for (int c = 0; c < C; ++c) {
            const float wgt = a[c] * inv;
            #pragma unroll
            for (int j = 0; j < 4; ++j)
                sacc[c][j] = fmaf(wgt, uh[c][j], sacc[c][j]);
        }
    }

    _Float16* sp = s_part + ((size_t)slot * B + b) * CO + kb * 4;
    #pragma unroll
    for (int c = 0; c < C; ++c) {
        f16x4 h = {(_Float16)sacc[c][0], (_Float16)sacc[c][1],
                   (_Float16)sacc[c][2], (_Float16)sacc[c][3]};
        *reinterpret_cast<f16x4*>(sp + c * O) = h;
    }
}

// Sum fp16 partials over nch slots, add bias, squash. Block = one (b, c).
__global__ __launch_bounds__(256)
void reduce_squash(const _Float16* __restrict__ s_part, const float* __restrict__ bias,
                   const float* __restrict__ vin_sum,
                   float* __restrict__ v_out, float* __restrict__ vsum_out, int nch)
{
    const int b = blockIdx.x;
    const int c = blockIdx.y;
    const int t = threadIdx.x;
    const int o = t & 15;
    const int q = t >> 4;            // 16 segments
    const int per = nch >> 4;

    float acc = 0.f;
    for (int k = 0; k < per; ++k) {
        const int blk = q * per + k;
        acc += (float)s_part[((size_t)blk * B + b) * CO + c * O + o];
    }
    __shared__ float red[16][O];
    red[q][o] = acc;
    __syncthreads();

    if (t < O) {
        float s = bias[c * O + o];
        #pragma unroll
        for (int k = 0; k < 16; ++k) s += red[k][o];
        float n = rowsum16(s * s);                     // ||s||^2 over o
        float v = s * sqrtf(n) / (1.f + n);            // squash
        const size_t idx = (size_t)b * CO + c * O + o;
        if (v_out)    v_out[idx] = v;
        if (vsum_out) vsum_out[idx] = (vin_sum ? vin_sum[idx] : 0.f) + v;
    }
}

extern "C" void kernel_launch(void* const* d_in, const int* in_sizes, int n_in,
                              void* d_out, int out_size, void* d_ws, size_t ws_size,
                              hipStream_t stream)
{
    const float* x    = (const float*)d_in[0];
    const float* W    = (const float*)d_in[1];
    const float* bias = (const float*)d_in[2];
    float* out = (float*)d_out;

    float* ws      = (float*)d_ws;
    float* vsumA   = ws;                                    // 20,480 f
    float* vsumB   = vsumA + (size_t)B * CO;                // 20,480 f
    _Float16* s_part = (_Float16*)(vsumB + (size_t)B * CO); // NSLOT*B*CO halves (21 MB)
    _Float16* W16    = s_part + (size_t)NSLOT * B * CO;     // 5,242,880 halves
    _Float16* xT16   = W16 + (size_t)R * C * O * IC;        // 4,194,304 halves
    // total ~40 MB

    dim3 p0g(NCHUNK * 2);    // 512 blocks (pass0, RCH=16 chunks)
    dim3 pg(NSLOT * 2);      // 1024 blocks (routing passes, RH=8 slots)
    dim3 rg(B, C);

    // iter 0: fused converts + uniform-0.1 K-packed GEMM (slots 0..255)
    pass0_fused<<<p0g, 256, 0, stream>>>(x, W, W16, xT16, s_part);
    reduce_squash<<<rg, 256, 0, stream>>>(s_part, bias, nullptr, nullptr, vsumA, NCHUNK);
    // iter 1: logits = uh . v0   (slots 0..511)
    pass_mfma<1><<<pg, 256, 0, stream>>>(W16, xT16, vsumA, s_part);
    reduce_squash<<<rg, 256, 0, stream>>>(s_part, bias, vsumA, nullptr, vsumB, NSLOT);
    // iter 2: logits = uh . (v0+v1)
    pass_mfma<2><<<pg, 256, 0, stream>>>(W16, xT16, vsumB, s_part);
    reduce_squash<<<rg, 256, 0, stream>>>(s_part, bias, nullptr, out, nullptr, NSLOT);
}

// Round 24
// 73.650 us; speedup vs baseline: 1.2337x; 1.2337x over previous
//
#include <hip/hip_runtime.h>
#include <math.h>

constexpr int B  = 128;
constexpr int R  = 4096;
constexpr int IC = 8;
constexpr int C  = 10;
constexpr int O  = 16;
constexpr int CO = C * O;        // 160

constexpr int RCH    = 16;       // r's per chunk (proven geometry)
constexpr int NCHUNK = R / RCH;  // 256

using f16x8 = __attribute__((ext_vector_type(8))) _Float16;
using f16x4 = __attribute__((ext_vector_type(4))) _Float16;
using f32x4 = __attribute__((ext_vector_type(4))) float;

// DPP add (VALU). row_ror:N = 0x120|N rotates within each 16-lane row.
template<int CTRL>
__device__ __forceinline__ float dpp_add(float v) {
    return v + __int_as_float(__builtin_amdgcn_update_dpp(
        0, __float_as_int(v), CTRL, 0xF, 0xF, true));
}
__device__ __forceinline__ float rowsum16(float v) {
    v = dpp_add<0x121>(v); v = dpp_add<0x122>(v);
    v = dpp_add<0x124>(v); v = dpp_add<0x128>(v);
    return v;
}

// Butterfly sum over lane^16 / lane^32 (proven DS path).
__device__ __forceinline__ float sum_kb(float p) {
    p += __int_as_float(__builtin_amdgcn_ds_swizzle(__float_as_int(p), 0x401F));
    p += __shfl_xor(p, 32, 64);
    return p;
}

// ---- pass 0 with fused conversion (replaces the separate convert kernel).
// Per (chunk, bhalf) block: convert the chunk's W fp32 slice -> wlds (+W16,
// written once by bhalf 0); read x [64b][16r][8i] as coalesced 512B rows,
// convert/transpose -> xlds, write xT16 coalesced from LDS; then the proven
// K-packed GEMM (uniform 0.1 weights, 4 r's per MFMA K=32) from LDS. ----
__global__ __launch_bounds__(256, 2)
void pass0_fused(const float* __restrict__ x, const float* __restrict__ W,
                 _Float16* __restrict__ W16, _Float16* __restrict__ xT16,
                 _Float16* __restrict__ s_part)
{
    __shared__ _Float16 wlds[RCH * C * O * IC];   // 40 KB: W[r][c][o][i]
    __shared__ _Float16 xlds[RCH * 64 * IC];      // 16 KB: x[r][b-local][i]

    const int tid = threadIdx.x;
    const int wv  = tid >> 6;
    const int l   = tid & 63;
    const int ln  = l & 15;
    const int kb  = l >> 4;

    const int g     = blockIdx.x;
    const int xcd   = g & 7;
    const int t     = g >> 3;          // 0..63
    const int bhalf = t & 1;
    const int cid   = t >> 1;          // 0..31
    const int chunk = xcd * 32 + cid;  // 0..255
    const int b     = bhalf * 64 + wv * 16 + ln;
    const int b0    = bhalf * 64;
    const int r0    = chunk * RCH;

    // ---- W slice: 20480 fp32 read coalesced, convert, stage + global write ----
    {
        const float* wsrc = W + (size_t)r0 * (C * O * IC);
        _Float16*    wdst = W16 + (size_t)r0 * (C * O * IC);
        #pragma unroll
        for (int k = 0; k < 20; ++k) {
            const int idx = (k * 256 + tid) * 4;
            float4 v = *reinterpret_cast<const float4*>(wsrc + idx);
            f16x4 h = {(_Float16)v.x, (_Float16)v.y, (_Float16)v.z, (_Float16)v.w};
            *reinterpret_cast<f16x4*>(&wlds[idx]) = h;
            if (bhalf == 0)
                *reinterpret_cast<f16x4*>(wdst + idx) = h;   // once per chunk
        }
    }
    // ---- x slice: 64 b-rows x 512B contiguous, convert+transpose into xlds ----
    {
        #pragma unroll
        for (int k = 0; k < 8; ++k) {
            const int w2 = k * 256 + tid;       // (bi, f4): 64 x 32 work items
            const int bi = w2 >> 5, f4 = w2 & 31;
            const int r = f4 >> 1, i4 = f4 & 1;
            float4 v = *reinterpret_cast<const float4*>(
                x + ((size_t)(b0 + bi) * R + r0 + r) * IC + i4 * 4);
            f16x4 h = {(_Float16)v.x, (_Float16)v.y, (_Float16)v.z, (_Float16)v.w};
            *reinterpret_cast<f16x4*>(&xlds[(r * 64 + bi) * IC + i4 * 4]) = h;
        }
    }
    __syncthreads();
    // ---- write xT16 (for passes 1,2) coalesced from xlds ----
    {
        #pragma unroll
        for (int k = 0; k < 4; ++k) {
            const int w2 = k * 256 + tid;       // 0..1023: (r, b-local)
            const int r = w2 >> 6, v = w2 & 63;
            *reinterpret_cast<f16x8*>(
                xT16 + ((size_t)(r0 + r) * B + b0 + v) * IC) =
                *reinterpret_cast<const f16x8*>(&xlds[(r * 64 + v) * IC]);
        }
    }

    // ---- K-packed GEMM from LDS (identical math to proven pass0_gemm) ----
    f32x4 sacc[C];
    #pragma unroll
    for (int c = 0; c < C; ++c) sacc[c] = (f32x4){0.f, 0.f, 0.f, 0.f};

    const int bloc = wv * 16 + ln;

    #pragma unroll 2
    for (int rp = 0; rp < RCH / 4; ++rp) {
        const int r = rp * 4 + kb;
        const f16x8 bf = *reinterpret_cast<const f16x8*>(&xlds[(r * 64 + bloc) * IC]);
        #pragma unroll
        for (int c = 0; c < C; ++c) {
            f16x8 af = *reinterpret_cast<const f16x8*>(
                &wlds[((r * C + c) * O + ln) * IC]);
            sacc[c] = __builtin_amdgcn_mfma_f32_16x16x32_f16(af, bf, sacc[c], 0, 0, 0);
        }
    }

    _Float16* sp = s_part + ((size_t)chunk * B + b) * CO + kb * 4;
    #pragma unroll
    for (int c = 0; c < C; ++c) {
        f16x4 h = {(_Float16)(sacc[c][0] * 0.1f), (_Float16)(sacc[c][1] * 0.1f),
                   (_Float16)(sacc[c][2] * 0.1f), (_Float16)(sacc[c][3] * 0.1f)};
        *reinterpret_cast<f16x4*>(sp + c * O) = h;
    }
}

// ---- routing pass (iters 1,2) with LDS-staged operands (R19/R21-proven) ----
template<int IT>
__global__ __launch_bounds__(256, 2)
void pass_mfma(const _Float16* __restrict__ W16, const _Float16* __restrict__ xT16,
               const float* __restrict__ vsum, _Float16* __restrict__ s_part)
{
    __shared__ _Float16 wlds[RCH * C * O * IC];   // 40 KB
    __shared__ _Float16 xlds[RCH * 64 * IC];      // 16 KB

    const int tid = threadIdx.x;
    const int wv  = tid >> 6;
    const int l   = tid & 63;
    const int ln  = l & 15;
    const int kb  = l >> 4;

    const int g     = blockIdx.x;
    const int xcd   = g & 7;
    const int t     = g >> 3;          // 0..63
    const int bhalf = t & 1;
    const int cid   = t >> 1;          // 0..31
    const int chunk = xcd * 32 + cid;  // 0..255
    const int b     = bhalf * 64 + wv * 16 + ln;
    const int r0    = chunk * RCH;

    {
        const _Float16* wsrc = W16 + (size_t)r0 * (C * O * IC);
        #pragma unroll
        for (int k = 0; k < 10; ++k) {
            const int idx = (k * 256 + tid) * 8;
            *reinterpret_cast<f16x8*>(&wlds[idx]) =
                *reinterpret_cast<const f16x8*>(wsrc + idx);
        }
    }
    {
        const int rr = tid >> 6, lx = tid & 63;
        #pragma unroll
        for (int k = 0; k < 4; ++k) {
            const int r = rr + k * 4;
            *reinterpret_cast<f16x8*>(&xlds[(r * 64 + lx) * IC]) =
                *reinterpret_cast<const f16x8*>(
                    xT16 + ((size_t)(r0 + r) * B + bhalf * 64 + lx) * IC);
        }
    }

    float vreg[C][4];                  // v[b][c][o = kb*4 + j]
    #pragma unroll
    for (int c = 0; c < C; ++c)
        *reinterpret_cast<float4*>(vreg[c]) =
            *reinterpret_cast<const float4*>(vsum + (size_t)b * CO + c * O + kb * 4);

    f32x4 sacc[C];
    #pragma unroll
    for (int c = 0; c < C; ++c) sacc[c] = (f32x4){0.f, 0.f, 0.f, 0.f};

    __syncthreads();

    const int bloc = wv * 16 + ln;

    #pragma unroll 2
    for (int rr = 0; rr < RCH; ++rr) {
        f16x8 bf;
        #pragma unroll
        for (int j = 0; j < 8; ++j) bf[j] = (_Float16)0.f;
        if (kb == 0)
            bf = *reinterpret_cast<const f16x8*>(&xlds[(rr * 64 + bloc) * IC]);

        f32x4 uh[C];
        #pragma unroll
        for (int c = 0; c < C; ++c) {
            f16x8 af = *reinterpret_cast<const f16x8*>(
                &wlds[((rr * C + c) * O + ln) * IC]);
            uh[c] = __builtin_amdgcn_mfma_f32_16x16x32_f16(
                        af, bf, (f32x4){0.f, 0.f, 0.f, 0.f}, 0, 0, 0);
        }

        float a[C];
        #pragma unroll
        for (int c = 0; c < C; ++c) {
            float p = uh[c][0] * vreg[c][0];
            p = fmaf(uh[c][1], vreg[c][1], p);
            p = fmaf(uh[c][2], vreg[c][2], p);
            p = fmaf(uh[c][3], vreg[c][3], p);
            a[c] = sum_kb(p);
        }
        float sum = 0.f;
        #pragma unroll
        for (int c = 0; c < C; ++c) { a[c] = __expf(a[c]); sum += a[c]; }
        const float inv = __builtin_amdgcn_rcpf(sum);
        #pragma unroll
        for (int c = 0; c < C; ++c) {
            const float wgt = a[c] * inv;
            #pragma unroll
            for (int j = 0; j < 4; ++j)
                sacc[c][j] = fmaf(wgt, uh[c][j], sacc[c][j]);
        }
    }

    _Float16* sp = s_part + ((size_t)chunk * B + b) * CO + kb * 4;
    #pragma unroll
    for (int c = 0; c < C; ++c) {
        f16x4 h = {(_Float16)sacc[c][0], (_Float16)sacc[c][1],
                   (_Float16)sacc[c][2], (_Float16)sacc[c][3]};
        *reinterpret_cast<f16x4*>(sp + c * O) = h;
    }
}

// Sum fp16 partials over chunks, add bias, squash. Block = one (b, c).
__global__ __launch_bounds__(256)
void reduce_squash(const _Float16* __restrict__ s_part, const float* __restrict__ bias,
                   const float* __restrict__ vin_sum,
                   float* __restrict__ v_out, float* __restrict__ vsum_out)
{
    const int b = blockIdx.x;
    const int c = blockIdx.y;
    const int t = threadIdx.x;
    const int o = t & 15;
    const int q = t >> 4;            // 16 segments of NCHUNK/16 chunks

    float acc = 0.f;
    for (int k = 0; k < NCHUNK / 16; ++k) {
        const int blk = q * (NCHUNK / 16) + k;
        acc += (float)s_part[((size_t)blk * B + b) * CO + c * O + o];
    }
    __shared__ float red[16][O];
    red[q][o] = acc;
    __syncthreads();

    if (t < O) {
        float s = bias[c * O + o];
        #pragma unroll
        for (int k = 0; k < 16; ++k) s += red[k][o];
        float n = rowsum16(s * s);                     // ||s||^2 over o
        float v = s * sqrtf(n) / (1.f + n);            // squash
        const size_t idx = (size_t)b * CO + c * O + o;
        if (v_out)    v_out[idx] = v;
        if (vsum_out) vsum_out[idx] = (vin_sum ? vin_sum[idx] : 0.f) + v;
    }
}

extern "C" void kernel_launch(void* const* d_in, const int* in_sizes, int n_in,
                              void* d_out, int out_size, void* d_ws, size_t ws_size,
                              hipStream_t stream)
{
    const float* x    = (const float*)d_in[0];
    const float* W    = (const float*)d_in[1];
    const float* bias = (const float*)d_in[2];
    float* out = (float*)d_out;

    float* ws      = (float*)d_ws;
    float* vsumA   = ws;                                    // 20,480 f
    float* vsumB   = vsumA + (size_t)B * CO;                // 20,480 f
    _Float16* s_part = (_Float16*)(vsumB + (size_t)B * CO); // 5,242,880 halves (10.5 MB)
    _Float16* W16    = s_part + (size_t)NCHUNK * B * CO;    // 5,242,880 halves
    _Float16* xT16   = W16 + (size_t)R * C * O * IC;        // 4,194,304 halves
    // total ~30 MB

    dim3 pg(NCHUNK * 2);     // 512 blocks, XCD-decoded in-kernel
    dim3 rg(B, C);

    // iter 0: fused converts + uniform-0.1 K-packed GEMM (writes W16/xT16 too)
    pass0_fused<<<pg, 256, 0, stream>>>(x, W, W16, xT16, s_part);
    reduce_squash<<<rg, 256, 0, stream>>>(s_part, bias, nullptr, nullptr, vsumA);  // vsumA = v0
    // iter 1: logits = uh . v0
    pass_mfma<1><<<pg, 256, 0, stream>>>(W16, xT16, vsumA, s_part);
    reduce_squash<<<rg, 256, 0, stream>>>(s_part, bias, vsumA, nullptr, vsumB);    // vsumB = v0+v1
    // iter 2: logits = uh . (v0+v1)
    pass_mfma<2><<<pg, 256, 0, stream>>>(W16, xT16, vsumB, s_part);
    reduce_squash<<<rg, 256, 0, stream>>>(s_part, bias, nullptr, out, nullptr);    // out = v2
}